// Round 5
// baseline (205.559 us; speedup 1.0000x reference)
//
#include <hip/hip_runtime.h>
#include <hip/hip_bf16.h>

#define B_  2
#define S_  2048
#define D_  1024
#define H_  16
#define HD_ 64

typedef __attribute__((ext_vector_type(8))) short short8;
typedef __attribute__((ext_vector_type(4))) float f32x4;

__device__ __forceinline__ unsigned short f2b(float f) {
    __hip_bfloat16 h = __float2bfloat16(f);
    unsigned short u;
    __builtin_memcpy(&u, &h, 2);
    return u;
}

// async global->LDS 16B per lane; LDS dest = wave-uniform base + lane*16
__device__ __forceinline__ void gl_lds16(const unsigned short* g, unsigned short* l) {
    __builtin_amdgcn_global_load_lds(
        (const __attribute__((address_space(1))) unsigned int*)g,
        (__attribute__((address_space(3))) unsigned int*)l, 16, 0, 0);
}

// ---------------------------------------------------------------------------
// Kernel 0: fp32 -> bf16 conversion for x, Wq, Wk, Wv, Wo into workspace.
// ---------------------------------------------------------------------------
__global__ __launch_bounds__(256) void convert_kernel(
    const float* __restrict__ x,  const float* __restrict__ Wq,
    const float* __restrict__ Wk, const float* __restrict__ Wv,
    const float* __restrict__ Wo, unsigned short* __restrict__ dst)
{
    const long long i4 = blockIdx.x * 256 + threadIdx.x;   // 0 .. 2M-1
    const long long e  = i4 * 4;
    const long long M1 = 1048576LL;
    const float* src;
    if      (e < 4 * M1) src = x  + e;
    else if (e < 5 * M1) src = Wq + (e - 4 * M1);
    else if (e < 6 * M1) src = Wk + (e - 5 * M1);
    else if (e < 7 * M1) src = Wv + (e - 6 * M1);
    else                 src = Wo + (e - 7 * M1);
    float4 v = *(const float4*)src;
    unsigned long long pk = (unsigned long long)f2b(v.x)
                          | ((unsigned long long)f2b(v.y) << 16)
                          | ((unsigned long long)f2b(v.z) << 32)
                          | ((unsigned long long)f2b(v.w) << 48);
    *(unsigned long long*)&dst[e] = pk;
}

// ---------------------------------------------------------------------------
// GEMM staging: 128x64 bf16 tile via global_load_lds, XOR-swizzled.
// Data (row, cb) lands at 16B-slot row*8 + (cb ^ (row&7)).
// ---------------------------------------------------------------------------
__device__ __forceinline__ void stage_tile_128x64(
    const unsigned short* __restrict__ gbase,  // tile row 0, col 0 (row stride D_)
    unsigned short* lds, int wave, int lane)
{
    const int r8 = lane >> 3;          // 0..7
    const int cb = (lane & 7) ^ r8;    // swizzled col-block
    #pragma unroll
    for (int t = 0; t < 4; ++t) {
        const int row = (wave * 4 + t) * 8 + r8;
        gl_lds16(gbase + row * D_ + cb * 8, lds + (wave * 4 + t) * 512);
    }
}

__device__ __forceinline__ short8 frag_ld(const unsigned short* lds, int row, int cbk) {
    return *(const short8*)&lds[(row * 8 + (cbk ^ (row & 7))) * 8];
}

// ---------------------------------------------------------------------------
// Kernel 1: QKV projection, 128x128 tile, BK=64, global_load_lds staging.
// Q (scaled 1/8), K -> [B][H][S][HD] ; V -> [B][H][HD][S] (pre-transposed)
// ---------------------------------------------------------------------------
__global__ __launch_bounds__(256) void qkv_proj_kernel(
    const unsigned short* __restrict__ x,
    const unsigned short* __restrict__ Wq,
    const unsigned short* __restrict__ Wk,
    const unsigned short* __restrict__ Wv,
    unsigned short* __restrict__ q_ws,
    unsigned short* __restrict__ k_ws,
    unsigned short* __restrict__ vT_ws)
{
    __shared__ unsigned short a_lds[128 * 64];
    __shared__ unsigned short b_lds[128 * 64];

    const int m0 = blockIdx.x * 128;
    const int n0 = blockIdx.y * 128;
    const int which = blockIdx.z;
    const unsigned short* W = (which == 0) ? Wq : (which == 1) ? Wk : Wv;

    const int tid  = threadIdx.x;
    const int wave = tid >> 6;
    const int lane = tid & 63;
    const int l15  = lane & 15;
    const int quad = lane >> 4;
    const int wm = (wave & 1) * 64;
    const int wn = (wave >> 1) * 64;

    f32x4 acc[4][4];
    #pragma unroll
    for (int sm = 0; sm < 4; ++sm)
        #pragma unroll
        for (int sn = 0; sn < 4; ++sn)
            #pragma unroll
            for (int r = 0; r < 4; ++r) acc[sm][sn][r] = 0.f;

    for (int kk = 0; kk < D_; kk += 64) {
        stage_tile_128x64(x + m0 * D_ + kk, a_lds, wave, lane);
        stage_tile_128x64(W + n0 * D_ + kk, b_lds, wave, lane);
        __syncthreads();
        #pragma unroll
        for (int kc = 0; kc < 2; ++kc) {
            short8 af[4], bf[4];
            #pragma unroll
            for (int s = 0; s < 4; ++s) {
                af[s] = frag_ld(a_lds, wm + s * 16 + l15, kc * 4 + quad);
                bf[s] = frag_ld(b_lds, wn + s * 16 + l15, kc * 4 + quad);
            }
            #pragma unroll
            for (int sm = 0; sm < 4; ++sm)
                #pragma unroll
                for (int sn = 0; sn < 4; ++sn)
                    acc[sm][sn] = __builtin_amdgcn_mfma_f32_16x16x32_bf16(
                        af[sm], bf[sn], acc[sm][sn], 0, 0, 0);
        }
        __syncthreads();
    }

    #pragma unroll
    for (int sm = 0; sm < 4; ++sm) {
        #pragma unroll
        for (int sn = 0; sn < 4; ++sn) {
            const int n  = n0 + wn + sn * 16 + l15;
            const int h  = n >> 6;
            const int hd = n & 63;
            const int mbase = m0 + wm + sm * 16 + quad * 4;
            const int b     = mbase >> 11;
            const int sbase = mbase & 2047;
            if (which == 2) {
                unsigned long long pk = 0;
                #pragma unroll
                for (int r = 0; r < 4; ++r)
                    pk |= (unsigned long long)f2b(acc[sm][sn][r]) << (16 * r);
                *(unsigned long long*)&vT_ws[((b * H_ + h) * HD_ + hd) * S_ + sbase] = pk;
            } else if (which == 0) {
                #pragma unroll
                for (int r = 0; r < 4; ++r)
                    q_ws[((b * H_ + h) * S_ + (sbase + r)) * HD_ + hd] =
                        f2b(acc[sm][sn][r] * 0.125f);
            } else {
                #pragma unroll
                for (int r = 0; r < 4; ++r)
                    k_ws[((b * H_ + h) * S_ + (sbase + r)) * HD_ + hd] =
                        f2b(acc[sm][sn][r]);
            }
        }
    }
}

// ---------------------------------------------------------------------------
// Kernel 2: causal flash attention, S^T formulation.
//   S^T = K·Q^T : lane owns ONE q column (l15), keys = f*16+quad*4+r.
//   Scalar online-softmax state; P^T -> B-frag via shuffle-then-select
//   (shuffle evaluates on SOURCE lane, so both f-candidates are shuffled
//   and the destination selects — the round-4 bug was selecting pre-shuffle).
//   O^T = V^T·P^T ; double-buffered K/V, pair-balanced blocks.
// ---------------------------------------------------------------------------
__global__ __launch_bounds__(256) void attn_kernel(
    const unsigned short* __restrict__ q_ws,
    const unsigned short* __restrict__ k_ws,
    const unsigned short* __restrict__ vT_ws,
    unsigned short* __restrict__ ctx_ws)   // [B*S][D], col = h*64+hd
{
    __shared__ unsigned short k_lds[2][64][72];
    __shared__ unsigned short vT_lds[2][64][72];
    __shared__ unsigned short q_lds[64][72];

    const int pair = blockIdx.x;   // 0..15
    const int bh   = blockIdx.y;   // 0..31

    const int tid  = threadIdx.x;
    const int wave = tid >> 6;
    const int lane = tid & 63;
    const int l15  = lane & 15;
    const int quad = lane >> 4;
    const int row  = tid >> 3;     // 0..31
    const int c8   = tid & 7;

    const unsigned short* Qh = q_ws + bh * (S_ * HD_);
    const unsigned short* Kh = k_ws + bh * (S_ * HD_);
    const unsigned short* Vt = vT_ws + bh * (HD_ * S_);
    const int b = bh >> 4;
    const int h = bh & 15;

    const int src0 = l15 + 32 * (quad & 1);   // source lane for j=0..3
    const int src1 = src0 + 16;               // source lane for j=4..7
    const int sel  = quad >> 1;               // which f-block this quad needs

    #pragma unroll
    for (int ph = 0; ph < 2; ++ph) {
        const int qt = (ph == 0) ? (31 - pair) : pair;
        const int q0 = qt * 64;
        const int qg = q0 + wave * 16 + l15;   // this lane's q row

        __syncthreads();   // previous phase readers done before restaging
        *(uint4*)&q_lds[row][c8 * 8]      = *(const uint4*)&Qh[(q0 + row) * HD_ + c8 * 8];
        *(uint4*)&q_lds[row + 32][c8 * 8] = *(const uint4*)&Qh[(q0 + row + 32) * HD_ + c8 * 8];
        *(uint4*)&k_lds[0][row][c8 * 8]       = *(const uint4*)&Kh[row * HD_ + c8 * 8];
        *(uint4*)&k_lds[0][row + 32][c8 * 8]  = *(const uint4*)&Kh[(row + 32) * HD_ + c8 * 8];
        *(uint4*)&vT_lds[0][row][c8 * 8]      = *(const uint4*)&Vt[row * S_ + c8 * 8];
        *(uint4*)&vT_lds[0][row + 32][c8 * 8] = *(const uint4*)&Vt[(row + 32) * S_ + c8 * 8];
        __syncthreads();

        short8 aq[2];   // Q as B-operand fragment
        aq[0] = *(const short8*)&q_lds[wave * 16 + l15][quad * 8];
        aq[1] = *(const short8*)&q_lds[wave * 16 + l15][32 + quad * 8];

        float M = -1e30f, l_lane = 0.f;
        f32x4 o[4];
        #pragma unroll
        for (int f = 0; f < 4; ++f)
            #pragma unroll
            for (int r = 0; r < 4; ++r) o[f][r] = 0.f;

        for (int kt = 0; kt <= qt; ++kt) {
            const int cur = kt & 1;
            if (kt < qt) {   // prefetch next K/V tile into other buffer
                const int nk0 = (kt + 1) * 64;
                const int nb  = cur ^ 1;
                *(uint4*)&k_lds[nb][row][c8 * 8]       = *(const uint4*)&Kh[(nk0 + row) * HD_ + c8 * 8];
                *(uint4*)&k_lds[nb][row + 32][c8 * 8]  = *(const uint4*)&Kh[(nk0 + row + 32) * HD_ + c8 * 8];
                *(uint4*)&vT_lds[nb][row][c8 * 8]      = *(const uint4*)&Vt[row * S_ + nk0 + c8 * 8];
                *(uint4*)&vT_lds[nb][row + 32][c8 * 8] = *(const uint4*)&Vt[(row + 32) * S_ + nk0 + c8 * 8];
            }

            // S^T[key][q] : key = kt*64 + f*16 + quad*4 + r, q = qg
            f32x4 sc[4];
            #pragma unroll
            for (int f = 0; f < 4; ++f)
                #pragma unroll
                for (int r = 0; r < 4; ++r) sc[f][r] = 0.f;
            #pragma unroll
            for (int f = 0; f < 4; ++f)
                #pragma unroll
                for (int kc = 0; kc < 2; ++kc) {
                    short8 ak = *(const short8*)&k_lds[cur][f * 16 + l15][kc * 32 + quad * 8];
                    sc[f] = __builtin_amdgcn_mfma_f32_16x16x32_bf16(ak, aq[kc], sc[f], 0, 0, 0);
                }

            float p[4][4];
            if (kt == qt) {   // diagonal tile: causal mask
                const int kbase = kt * 64 + quad * 4;
                #pragma unroll
                for (int f = 0; f < 4; ++f)
                    #pragma unroll
                    for (int r = 0; r < 4; ++r)
                        p[f][r] = (kbase + f * 16 + r > qg) ? -1e30f : sc[f][r];
            } else {
                #pragma unroll
                for (int f = 0; f < 4; ++f)
                    #pragma unroll
                    for (int r = 0; r < 4; ++r) p[f][r] = sc[f][r];
            }

            // scalar online softmax (this lane's q column)
            float mloc = -1e30f;
            #pragma unroll
            for (int f = 0; f < 4; ++f)
                #pragma unroll
                for (int r = 0; r < 4; ++r) mloc = fmaxf(mloc, p[f][r]);
            mloc = fmaxf(mloc, __shfl_xor(mloc, 16, 64));
            mloc = fmaxf(mloc, __shfl_xor(mloc, 32, 64));

            const float Mn = fmaxf(M, mloc);
            const float alpha = __expf(M - Mn);
            M = Mn;

            float rs = 0.f;
            #pragma unroll
            for (int f = 0; f < 4; ++f)
                #pragma unroll
                for (int r = 0; r < 4; ++r) {
                    p[f][r] = __expf(p[f][r] - M);
                    rs += p[f][r];
                }
            l_lane = l_lane * alpha + rs;

            #pragma unroll
            for (int f = 0; f < 4; ++f)
                #pragma unroll
                for (int r = 0; r < 4; ++r) o[f][r] *= alpha;

            // pack P^T rows as bf16 dword pairs: pd[f][0]=(r0,r1), pd[f][1]=(r2,r3)
            unsigned int pd[4][2];
            #pragma unroll
            for (int f = 0; f < 4; ++f) {
                pd[f][0] = (unsigned int)f2b(p[f][0]) | ((unsigned int)f2b(p[f][1]) << 16);
                pd[f][1] = (unsigned int)f2b(p[f][2]) | ((unsigned int)f2b(p[f][3]) << 16);
            }

            // P^T B-fragment: shuffle BOTH f-candidates, select on destination.
            #pragma unroll
            for (int c = 0; c < 2; ++c) {
                const int a0 = __shfl((int)pd[c * 2][0],     src0, 64);
                const int a1 = __shfl((int)pd[c * 2][1],     src0, 64);
                const int a2 = __shfl((int)pd[c * 2][0],     src1, 64);
                const int a3 = __shfl((int)pd[c * 2][1],     src1, 64);
                const int b0 = __shfl((int)pd[c * 2 + 1][0], src0, 64);
                const int b1 = __shfl((int)pd[c * 2 + 1][1], src0, 64);
                const int b2 = __shfl((int)pd[c * 2 + 1][0], src1, 64);
                const int b3 = __shfl((int)pd[c * 2 + 1][1], src1, 64);
                union { int i[4]; short8 s; } u;
                u.i[0] = sel ? b0 : a0;
                u.i[1] = sel ? b1 : a1;
                u.i[2] = sel ? b2 : a2;
                u.i[3] = sel ? b3 : a3;
                #pragma unroll
                for (int f = 0; f < 4; ++f) {
                    short8 av = *(const short8*)&vT_lds[cur][f * 16 + l15][c * 32 + quad * 8];
                    o[f] = __builtin_amdgcn_mfma_f32_16x16x32_bf16(av, u.s, o[f], 0, 0, 0);
                }
            }

            __syncthreads();   // buf[cur] readers done; prefetch visible
        }

        // final l reduction across quads + ctx write (O^T: hd=f*16+quad*4+r, q=l15)
        float l = l_lane;
        l += __shfl_xor(l, 16, 64);
        l += __shfl_xor(l, 32, 64);
        const float inv_l = 1.0f / l;

        #pragma unroll
        for (int f = 0; f < 4; ++f) {
            unsigned long long pk = 0;
            #pragma unroll
            for (int r = 0; r < 4; ++r)
                pk |= (unsigned long long)f2b(o[f][r] * inv_l) << (16 * r);
            *(unsigned long long*)&ctx_ws[(b * S_ + qg) * D_ + h * 64 + f * 16 + quad * 4] = pk;
        }
    }
}

// ---------------------------------------------------------------------------
// Kernel 3: output projection + bias, 128x128 tile, global_load_lds staging.
// ---------------------------------------------------------------------------
__global__ __launch_bounds__(256) void out_proj_kernel(
    const unsigned short* __restrict__ ctx,
    const unsigned short* __restrict__ Wo,
    const float* __restrict__ bo,
    float* __restrict__ out)
{
    __shared__ unsigned short a_lds[128 * 64];
    __shared__ unsigned short b_lds[128 * 64];

    const int m0 = blockIdx.x * 128;
    const int n0 = blockIdx.y * 128;

    const int tid  = threadIdx.x;
    const int wave = tid >> 6;
    const int lane = tid & 63;
    const int l15  = lane & 15;
    const int quad = lane >> 4;
    const int wm = (wave & 1) * 64;
    const int wn = (wave >> 1) * 64;

    f32x4 acc[4][4];
    #pragma unroll
    for (int sm = 0; sm < 4; ++sm)
        #pragma unroll
        for (int sn = 0; sn < 4; ++sn)
            #pragma unroll
            for (int r = 0; r < 4; ++r) acc[sm][sn][r] = 0.f;

    for (int kk = 0; kk < D_; kk += 64) {
        stage_tile_128x64(ctx + m0 * D_ + kk, a_lds, wave, lane);
        stage_tile_128x64(Wo + n0 * D_ + kk, b_lds, wave, lane);
        __syncthreads();
        #pragma unroll
        for (int kc = 0; kc < 2; ++kc) {
            short8 af[4], bf[4];
            #pragma unroll
            for (int s = 0; s < 4; ++s) {
                af[s] = frag_ld(a_lds, wm + s * 16 + l15, kc * 4 + quad);
                bf[s] = frag_ld(b_lds, wn + s * 16 + l15, kc * 4 + quad);
            }
            #pragma unroll
            for (int sm = 0; sm < 4; ++sm)
                #pragma unroll
                for (int sn = 0; sn < 4; ++sn)
                    acc[sm][sn] = __builtin_amdgcn_mfma_f32_16x16x32_bf16(
                        af[sm], bf[sn], acc[sm][sn], 0, 0, 0);
        }
        __syncthreads();
    }

    #pragma unroll
    for (int sm = 0; sm < 4; ++sm) {
        #pragma unroll
        for (int sn = 0; sn < 4; ++sn) {
            const int n = n0 + wn + sn * 16 + l15;
            const float bias = bo[n];
            const int mbase = m0 + wm + sm * 16 + quad * 4;
            #pragma unroll
            for (int r = 0; r < 4; ++r)
                out[(mbase + r) * D_ + n] = acc[sm][sn][r] + bias;
        }
    }
}

// ---------------------------------------------------------------------------
extern "C" void kernel_launch(void* const* d_in, const int* in_sizes, int n_in,
                              void* d_out, int out_size, void* d_ws, size_t ws_size,
                              hipStream_t stream) {
    const float* x  = (const float*)d_in[0];
    const float* Wq = (const float*)d_in[1];
    const float* Wk = (const float*)d_in[2];
    const float* Wv = (const float*)d_in[3];
    const float* Wo = (const float*)d_in[4];
    const float* bo = (const float*)d_in[5];
    float* out = (float*)d_out;

    const size_t M1 = 1048576;           // 1M elements
    const size_t SZ = 4 * M1;            // B*S*D = 4M elements

    unsigned short* xb  = (unsigned short*)d_ws;     // 4M
    unsigned short* wqb = xb  + SZ;                  // 1M
    unsigned short* wkb = wqb + M1;                  // 1M
    unsigned short* wvb = wkb + M1;                  // 1M
    unsigned short* wob = wvb + M1;                  // 1M
    unsigned short* q_ws   = wob + M1;               // 4M
    unsigned short* k_ws   = q_ws + SZ;              // 4M
    unsigned short* vT_ws  = k_ws + SZ;              // 4M
    unsigned short* ctx_ws = vT_ws + SZ;             // 4M  (total 24M u16 = 48MB)

    convert_kernel<<<dim3(8192), 256, 0, stream>>>(x, Wq, Wk, Wv, Wo, xb);
    qkv_proj_kernel<<<dim3(32, 8, 3), 256, 0, stream>>>(xb, wqb, wkb, wvb, q_ws, k_ws, vT_ws);
    attn_kernel<<<dim3(16, 32), 256, 0, stream>>>(q_ws, k_ws, vT_ws, ctx_ws);
    out_proj_kernel<<<dim3(32, 8), 256, 0, stream>>>(ctx_ws, wob, bo, out);
}

// Round 6
// 198.309 us; speedup vs baseline: 1.0366x; 1.0366x over previous
//
#include <hip/hip_runtime.h>
#include <hip/hip_bf16.h>

#define B_  2
#define S_  2048
#define D_  1024
#define H_  16
#define HD_ 64

typedef __attribute__((ext_vector_type(8))) short short8;
typedef __attribute__((ext_vector_type(4))) float f32x4;

__device__ __forceinline__ unsigned short f2b(float f) {
    __hip_bfloat16 h = __float2bfloat16(f);
    unsigned short u;
    __builtin_memcpy(&u, &h, 2);
    return u;
}

// ---------------------------------------------------------------------------
// Kernel 0: fp32 -> bf16 conversion for x, Wq, Wk, Wv, Wo into workspace.
// ---------------------------------------------------------------------------
__global__ __launch_bounds__(256) void convert_kernel(
    const float* __restrict__ x,  const float* __restrict__ Wq,
    const float* __restrict__ Wk, const float* __restrict__ Wv,
    const float* __restrict__ Wo, unsigned short* __restrict__ dst)
{
    const long long i4 = blockIdx.x * 256 + threadIdx.x;   // 0 .. 2M-1
    const long long e  = i4 * 4;
    const long long M1 = 1048576LL;
    const float* src;
    if      (e < 4 * M1) src = x  + e;
    else if (e < 5 * M1) src = Wq + (e - 4 * M1);
    else if (e < 6 * M1) src = Wk + (e - 5 * M1);
    else if (e < 7 * M1) src = Wv + (e - 6 * M1);
    else                 src = Wo + (e - 7 * M1);
    float4 v = *(const float4*)src;
    unsigned long long pk = (unsigned long long)f2b(v.x)
                          | ((unsigned long long)f2b(v.y) << 16)
                          | ((unsigned long long)f2b(v.z) << 32)
                          | ((unsigned long long)f2b(v.w) << 48);
    *(unsigned long long*)&dst[e] = pk;
}

// ---------------------------------------------------------------------------
// Kernel 1: QKV projection, 128x128 tile, BK=64, vector-load staging
// (round-3 structure: measured faster than global_load_lds for this shape).
// Q (scaled 1/8), K -> [B][H][S][HD] ; V -> [B][H][HD][S] (pre-transposed)
// ---------------------------------------------------------------------------
__global__ __launch_bounds__(256) void qkv_proj_kernel(
    const unsigned short* __restrict__ x,
    const unsigned short* __restrict__ Wq,
    const unsigned short* __restrict__ Wk,
    const unsigned short* __restrict__ Wv,
    unsigned short* __restrict__ q_ws,
    unsigned short* __restrict__ k_ws,
    unsigned short* __restrict__ vT_ws)
{
    __shared__ unsigned short a_lds[128][72];
    __shared__ unsigned short b_lds[128][72];

    const int m0 = blockIdx.x * 128;
    const int n0 = blockIdx.y * 128;
    const int which = blockIdx.z;
    const unsigned short* W = (which == 0) ? Wq : (which == 1) ? Wk : Wv;

    const int tid  = threadIdx.x;
    const int wave = tid >> 6;
    const int lane = tid & 63;
    const int l15  = lane & 15;
    const int quad = lane >> 4;
    const int wm = (wave & 1) * 64;
    const int wn = (wave >> 1) * 64;

    f32x4 acc[4][4];
    #pragma unroll
    for (int sm = 0; sm < 4; ++sm)
        #pragma unroll
        for (int sn = 0; sn < 4; ++sn)
            #pragma unroll
            for (int r = 0; r < 4; ++r) acc[sm][sn][r] = 0.f;

    const int row = tid >> 3;   // 0..31
    const int c8  = tid & 7;    // 0..7

    for (int kk = 0; kk < D_; kk += 64) {
        #pragma unroll
        for (int rp = 0; rp < 4; ++rp) {
            *(uint4*)&a_lds[row + rp * 32][c8 * 8] =
                *(const uint4*)&x[(m0 + row + rp * 32) * D_ + kk + c8 * 8];
            *(uint4*)&b_lds[row + rp * 32][c8 * 8] =
                *(const uint4*)&W[(n0 + row + rp * 32) * D_ + kk + c8 * 8];
        }
        __syncthreads();
        #pragma unroll
        for (int kc = 0; kc < 2; ++kc) {
            short8 af[4], bf[4];
            #pragma unroll
            for (int s = 0; s < 4; ++s) {
                af[s] = *(const short8*)&a_lds[wm + s * 16 + l15][kc * 32 + quad * 8];
                bf[s] = *(const short8*)&b_lds[wn + s * 16 + l15][kc * 32 + quad * 8];
            }
            #pragma unroll
            for (int sm = 0; sm < 4; ++sm)
                #pragma unroll
                for (int sn = 0; sn < 4; ++sn)
                    acc[sm][sn] = __builtin_amdgcn_mfma_f32_16x16x32_bf16(
                        af[sm], bf[sn], acc[sm][sn], 0, 0, 0);
        }
        __syncthreads();
    }

    // epilogue: D[row=quad*4+r][col=l15]; Q gets the 1/sqrt(HD) fold
    #pragma unroll
    for (int sm = 0; sm < 4; ++sm) {
        #pragma unroll
        for (int sn = 0; sn < 4; ++sn) {
            const int n  = n0 + wn + sn * 16 + l15;
            const int h  = n >> 6;
            const int hd = n & 63;
            const int mbase = m0 + wm + sm * 16 + quad * 4;
            const int b     = mbase >> 11;
            const int sbase = mbase & 2047;
            if (which == 2) {
                unsigned long long pk = 0;
                #pragma unroll
                for (int r = 0; r < 4; ++r)
                    pk |= (unsigned long long)f2b(acc[sm][sn][r]) << (16 * r);
                *(unsigned long long*)&vT_ws[((b * H_ + h) * HD_ + hd) * S_ + sbase] = pk;
            } else if (which == 0) {
                #pragma unroll
                for (int r = 0; r < 4; ++r)
                    q_ws[((b * H_ + h) * S_ + (sbase + r)) * HD_ + hd] =
                        f2b(acc[sm][sn][r] * 0.125f);
            } else {
                #pragma unroll
                for (int r = 0; r < 4; ++r)
                    k_ws[((b * H_ + h) * S_ + (sbase + r)) * HD_ + hd] =
                        f2b(acc[sm][sn][r]);
            }
        }
    }
}

// ---------------------------------------------------------------------------
// Kernel 2: causal flash attention, S^T formulation (round-5, verified).
//   S^T = K·Q^T : lane owns ONE q column (l15), keys = f*16+quad*4+r.
//   Scalar online-softmax state; P^T -> B-frag via shuffle-then-select.
//   O^T = V^T·P^T ; double-buffered K/V, pair-balanced blocks.
// ---------------------------------------------------------------------------
__global__ __launch_bounds__(256) void attn_kernel(
    const unsigned short* __restrict__ q_ws,
    const unsigned short* __restrict__ k_ws,
    const unsigned short* __restrict__ vT_ws,
    unsigned short* __restrict__ ctx_ws)   // [B*S][D], col = h*64+hd
{
    __shared__ unsigned short k_lds[2][64][72];
    __shared__ unsigned short vT_lds[2][64][72];
    __shared__ unsigned short q_lds[64][72];

    const int pair = blockIdx.x;   // 0..15
    const int bh   = blockIdx.y;   // 0..31

    const int tid  = threadIdx.x;
    const int wave = tid >> 6;
    const int lane = tid & 63;
    const int l15  = lane & 15;
    const int quad = lane >> 4;
    const int row  = tid >> 3;     // 0..31
    const int c8   = tid & 7;

    const unsigned short* Qh = q_ws + bh * (S_ * HD_);
    const unsigned short* Kh = k_ws + bh * (S_ * HD_);
    const unsigned short* Vt = vT_ws + bh * (HD_ * S_);
    const int b = bh >> 4;
    const int h = bh & 15;

    const int src0 = l15 + 32 * (quad & 1);   // source lane for j=0..3
    const int src1 = src0 + 16;               // source lane for j=4..7
    const int sel  = quad >> 1;               // which f-block this quad needs

    #pragma unroll
    for (int ph = 0; ph < 2; ++ph) {
        const int qt = (ph == 0) ? (31 - pair) : pair;
        const int q0 = qt * 64;
        const int qg = q0 + wave * 16 + l15;   // this lane's q row

        __syncthreads();   // previous phase readers done before restaging
        *(uint4*)&q_lds[row][c8 * 8]      = *(const uint4*)&Qh[(q0 + row) * HD_ + c8 * 8];
        *(uint4*)&q_lds[row + 32][c8 * 8] = *(const uint4*)&Qh[(q0 + row + 32) * HD_ + c8 * 8];
        *(uint4*)&k_lds[0][row][c8 * 8]       = *(const uint4*)&Kh[row * HD_ + c8 * 8];
        *(uint4*)&k_lds[0][row + 32][c8 * 8]  = *(const uint4*)&Kh[(row + 32) * HD_ + c8 * 8];
        *(uint4*)&vT_lds[0][row][c8 * 8]      = *(const uint4*)&Vt[row * S_ + c8 * 8];
        *(uint4*)&vT_lds[0][row + 32][c8 * 8] = *(const uint4*)&Vt[(row + 32) * S_ + c8 * 8];
        __syncthreads();

        short8 aq[2];   // Q as B-operand fragment
        aq[0] = *(const short8*)&q_lds[wave * 16 + l15][quad * 8];
        aq[1] = *(const short8*)&q_lds[wave * 16 + l15][32 + quad * 8];

        float M = -1e30f, l_lane = 0.f;
        f32x4 o[4];
        #pragma unroll
        for (int f = 0; f < 4; ++f)
            #pragma unroll
            for (int r = 0; r < 4; ++r) o[f][r] = 0.f;

        for (int kt = 0; kt <= qt; ++kt) {
            const int cur = kt & 1;
            if (kt < qt) {   // prefetch next K/V tile into other buffer
                const int nk0 = (kt + 1) * 64;
                const int nb  = cur ^ 1;
                *(uint4*)&k_lds[nb][row][c8 * 8]       = *(const uint4*)&Kh[(nk0 + row) * HD_ + c8 * 8];
                *(uint4*)&k_lds[nb][row + 32][c8 * 8]  = *(const uint4*)&Kh[(nk0 + row + 32) * HD_ + c8 * 8];
                *(uint4*)&vT_lds[nb][row][c8 * 8]      = *(const uint4*)&Vt[row * S_ + nk0 + c8 * 8];
                *(uint4*)&vT_lds[nb][row + 32][c8 * 8] = *(const uint4*)&Vt[(row + 32) * S_ + nk0 + c8 * 8];
            }

            // S^T[key][q] : key = kt*64 + f*16 + quad*4 + r, q = qg
            f32x4 sc[4];
            #pragma unroll
            for (int f = 0; f < 4; ++f)
                #pragma unroll
                for (int r = 0; r < 4; ++r) sc[f][r] = 0.f;
            #pragma unroll
            for (int f = 0; f < 4; ++f)
                #pragma unroll
                for (int kc = 0; kc < 2; ++kc) {
                    short8 ak = *(const short8*)&k_lds[cur][f * 16 + l15][kc * 32 + quad * 8];
                    sc[f] = __builtin_amdgcn_mfma_f32_16x16x32_bf16(ak, aq[kc], sc[f], 0, 0, 0);
                }

            float p[4][4];
            if (kt == qt) {   // diagonal tile: causal mask
                const int kbase = kt * 64 + quad * 4;
                #pragma unroll
                for (int f = 0; f < 4; ++f)
                    #pragma unroll
                    for (int r = 0; r < 4; ++r)
                        p[f][r] = (kbase + f * 16 + r > qg) ? -1e30f : sc[f][r];
            } else {
                #pragma unroll
                for (int f = 0; f < 4; ++f)
                    #pragma unroll
                    for (int r = 0; r < 4; ++r) p[f][r] = sc[f][r];
            }

            // scalar online softmax (this lane's q column)
            float mloc = -1e30f;
            #pragma unroll
            for (int f = 0; f < 4; ++f)
                #pragma unroll
                for (int r = 0; r < 4; ++r) mloc = fmaxf(mloc, p[f][r]);
            mloc = fmaxf(mloc, __shfl_xor(mloc, 16, 64));
            mloc = fmaxf(mloc, __shfl_xor(mloc, 32, 64));

            const float Mn = fmaxf(M, mloc);
            const float alpha = __expf(M - Mn);
            M = Mn;

            float rs = 0.f;
            #pragma unroll
            for (int f = 0; f < 4; ++f)
                #pragma unroll
                for (int r = 0; r < 4; ++r) {
                    p[f][r] = __expf(p[f][r] - M);
                    rs += p[f][r];
                }
            l_lane = l_lane * alpha + rs;

            #pragma unroll
            for (int f = 0; f < 4; ++f)
                #pragma unroll
                for (int r = 0; r < 4; ++r) o[f][r] *= alpha;

            // pack P^T rows as bf16 dword pairs: pd[f][0]=(r0,r1), pd[f][1]=(r2,r3)
            unsigned int pd[4][2];
            #pragma unroll
            for (int f = 0; f < 4; ++f) {
                pd[f][0] = (unsigned int)f2b(p[f][0]) | ((unsigned int)f2b(p[f][1]) << 16);
                pd[f][1] = (unsigned int)f2b(p[f][2]) | ((unsigned int)f2b(p[f][3]) << 16);
            }

            // P^T B-fragment: shuffle BOTH f-candidates, select on destination.
            #pragma unroll
            for (int c = 0; c < 2; ++c) {
                const int a0 = __shfl((int)pd[c * 2][0],     src0, 64);
                const int a1 = __shfl((int)pd[c * 2][1],     src0, 64);
                const int a2 = __shfl((int)pd[c * 2][0],     src1, 64);
                const int a3 = __shfl((int)pd[c * 2][1],     src1, 64);
                const int b0 = __shfl((int)pd[c * 2 + 1][0], src0, 64);
                const int b1 = __shfl((int)pd[c * 2 + 1][1], src0, 64);
                const int b2 = __shfl((int)pd[c * 2 + 1][0], src1, 64);
                const int b3 = __shfl((int)pd[c * 2 + 1][1], src1, 64);
                union { int i[4]; short8 s; } u;
                u.i[0] = sel ? b0 : a0;
                u.i[1] = sel ? b1 : a1;
                u.i[2] = sel ? b2 : a2;
                u.i[3] = sel ? b3 : a3;
                #pragma unroll
                for (int f = 0; f < 4; ++f) {
                    short8 av = *(const short8*)&vT_lds[cur][f * 16 + l15][c * 32 + quad * 8];
                    o[f] = __builtin_amdgcn_mfma_f32_16x16x32_bf16(av, u.s, o[f], 0, 0, 0);
                }
            }

            __syncthreads();   // buf[cur] readers done; prefetch visible
        }

        // final l reduction across quads + ctx write (O^T: hd=f*16+quad*4+r, q=l15)
        float l = l_lane;
        l += __shfl_xor(l, 16, 64);
        l += __shfl_xor(l, 32, 64);
        const float inv_l = 1.0f / l;

        #pragma unroll
        for (int f = 0; f < 4; ++f) {
            unsigned long long pk = 0;
            #pragma unroll
            for (int r = 0; r < 4; ++r)
                pk |= (unsigned long long)f2b(o[f][r] * inv_l) << (16 * r);
            *(unsigned long long*)&ctx_ws[(b * S_ + qg) * D_ + h * 64 + f * 16 + quad * 4] = pk;
        }
    }
}

// ---------------------------------------------------------------------------
// Kernel 3: output projection + bias, 128x128 tile, vector-load staging.
// ---------------------------------------------------------------------------
__global__ __launch_bounds__(256) void out_proj_kernel(
    const unsigned short* __restrict__ ctx,
    const unsigned short* __restrict__ Wo,
    const float* __restrict__ bo,
    float* __restrict__ out)
{
    __shared__ unsigned short a_lds[128][72];
    __shared__ unsigned short b_lds[128][72];

    const int m0 = blockIdx.x * 128;
    const int n0 = blockIdx.y * 128;

    const int tid  = threadIdx.x;
    const int wave = tid >> 6;
    const int lane = tid & 63;
    const int l15  = lane & 15;
    const int quad = lane >> 4;
    const int wm = (wave & 1) * 64;
    const int wn = (wave >> 1) * 64;

    f32x4 acc[4][4];
    #pragma unroll
    for (int sm = 0; sm < 4; ++sm)
        #pragma unroll
        for (int sn = 0; sn < 4; ++sn)
            #pragma unroll
            for (int r = 0; r < 4; ++r) acc[sm][sn][r] = 0.f;

    const int row = tid >> 3;
    const int c8  = tid & 7;

    for (int kk = 0; kk < D_; kk += 64) {
        #pragma unroll
        for (int rp = 0; rp < 4; ++rp) {
            *(uint4*)&a_lds[row + rp * 32][c8 * 8] =
                *(const uint4*)&ctx[(m0 + row + rp * 32) * D_ + kk + c8 * 8];
            *(uint4*)&b_lds[row + rp * 32][c8 * 8] =
                *(const uint4*)&Wo[(n0 + row + rp * 32) * D_ + kk + c8 * 8];
        }
        __syncthreads();
        #pragma unroll
        for (int kc = 0; kc < 2; ++kc) {
            short8 af[4], bf[4];
            #pragma unroll
            for (int s = 0; s < 4; ++s) {
                af[s] = *(const short8*)&a_lds[wm + s * 16 + l15][kc * 32 + quad * 8];
                bf[s] = *(const short8*)&b_lds[wn + s * 16 + l15][kc * 32 + quad * 8];
            }
            #pragma unroll
            for (int sm = 0; sm < 4; ++sm)
                #pragma unroll
                for (int sn = 0; sn < 4; ++sn)
                    acc[sm][sn] = __builtin_amdgcn_mfma_f32_16x16x32_bf16(
                        af[sm], bf[sn], acc[sm][sn], 0, 0, 0);
        }
        __syncthreads();
    }

    #pragma unroll
    for (int sm = 0; sm < 4; ++sm) {
        #pragma unroll
        for (int sn = 0; sn < 4; ++sn) {
            const int n = n0 + wn + sn * 16 + l15;
            const float bias = bo[n];
            const int mbase = m0 + wm + sm * 16 + quad * 4;
            #pragma unroll
            for (int r = 0; r < 4; ++r)
                out[(mbase + r) * D_ + n] = acc[sm][sn][r] + bias;
        }
    }
}

// ---------------------------------------------------------------------------
extern "C" void kernel_launch(void* const* d_in, const int* in_sizes, int n_in,
                              void* d_out, int out_size, void* d_ws, size_t ws_size,
                              hipStream_t stream) {
    const float* x  = (const float*)d_in[0];
    const float* Wq = (const float*)d_in[1];
    const float* Wk = (const float*)d_in[2];
    const float* Wv = (const float*)d_in[3];
    const float* Wo = (const float*)d_in[4];
    const float* bo = (const float*)d_in[5];
    float* out = (float*)d_out;

    const size_t M1 = 1048576;           // 1M elements
    const size_t SZ = 4 * M1;            // B*S*D = 4M elements

    unsigned short* xb  = (unsigned short*)d_ws;     // 4M
    unsigned short* wqb = xb  + SZ;                  // 1M
    unsigned short* wkb = wqb + M1;                  // 1M
    unsigned short* wvb = wkb + M1;                  // 1M
    unsigned short* wob = wvb + M1;                  // 1M
    unsigned short* q_ws   = wob + M1;               // 4M
    unsigned short* k_ws   = q_ws + SZ;              // 4M
    unsigned short* vT_ws  = k_ws + SZ;              // 4M
    unsigned short* ctx_ws = vT_ws + SZ;             // 4M  (total 24M u16 = 48MB)

    convert_kernel<<<dim3(8192), 256, 0, stream>>>(x, Wq, Wk, Wv, Wo, xb);
    qkv_proj_kernel<<<dim3(32, 8, 3), 256, 0, stream>>>(xb, wqb, wkb, wvb, q_ws, k_ws, vT_ws);
    attn_kernel<<<dim3(16, 32), 256, 0, stream>>>(q_ws, k_ws, vT_ws, ctx_ws);
    out_proj_kernel<<<dim3(32, 8), 256, 0, stream>>>(ctx_ws, wob, bo, out);
}